// Round 4
// baseline (183.097 us; speedup 1.0000x reference)
//
#include <hip/hip_runtime.h>

// grid [2,160,160,160,3] fp32; interior outputs (i,j,k) in 2..157 per axis.
//
// Register-pipelined x-march (each staged slice read from LDS exactly once):
//   - within-slice terms (hzz*, hyy*, hyz*) emitted at x = i      (s in [2,13])
//   - hxy*/hxz* at x = i+1 from dy/dz pipelined 2 steps (parity)  (s in [3,14])
//   - hxx0 at x = i+2 from v0 pipelined 4 steps                    (s >= 4)
// LDS slices are FULL-Z AoS rows (480 contiguous floats per y-row):
//   staging is one contiguous 3840-float global slab per slice -> coalesced
//   float4 loads + lane-linear ds_write_b128; compute reads are 16B-aligned
//   ds_read_b128.
// R4: JT 6->4 (NROW 8), SLICEF unpadded 3840 -> 30.7KB LDS -> 5 blocks/CU
// residency; grid 676->1014 (~4 sustained/CU) to fill DS-pipe barrier gaps
// (R3 was grid-limited at 2.6 blocks/CU, OccupancyPercent 20%).
#define OY 480                    // floats per y-row (160 z * 3 comps)
#define OX 76800                  // floats per x-slice
#define SB 12288000               // floats per batch
#define JT 4                      // output rows (y) per block; 39 tiles
#define NROW 8                    // JT + 4 halo rows
#define IT 12                     // output slices (x) per block; 13 segs
#define NSEG 13
#define SLICEF 3840               // floats per slice buffer (8 rows * 480)
#define CTHR 156                  // 4 rows * 39 z-quads (V=4 outputs each)
#define NBLK 1014                 // 2 * 39 * 13
#define INV_SIZE (1.0f/22778496.0f)  // 2*156^3*3

__device__ __forceinline__ float4 ld4p(const float* p){ return *reinterpret_cast<const float4*>(p); }
__device__ __forceinline__ void st4p(float* p, float4 v){ *reinterpret_cast<float4*>(p) = v; }

__device__ __forceinline__ void ld24(float* d, const float* p){
    float4 x0=ld4p(p), x1=ld4p(p+4), x2=ld4p(p+8), x3=ld4p(p+12), x4=ld4p(p+16), x5=ld4p(p+20);
    d[0]=x0.x; d[1]=x0.y; d[2]=x0.z; d[3]=x0.w;
    d[4]=x1.x; d[5]=x1.y; d[6]=x1.z; d[7]=x1.w;
    d[8]=x2.x; d[9]=x2.y; d[10]=x2.z; d[11]=x2.w;
    d[12]=x3.x; d[13]=x3.y; d[14]=x3.z; d[15]=x3.w;
    d[16]=x4.x; d[17]=x4.y; d[18]=x4.z; d[19]=x4.w;
    d[20]=x5.x; d[21]=x5.y; d[22]=x5.z; d[23]=x5.w;
}
__device__ __forceinline__ void ld16(float* d, const float* p){
    float4 x0=ld4p(p), x1=ld4p(p+4), x2=ld4p(p+8), x3=ld4p(p+12);
    d[0]=x0.x; d[1]=x0.y; d[2]=x0.z; d[3]=x0.w;
    d[4]=x1.x; d[5]=x1.y; d[6]=x1.z; d[7]=x1.w;
    d[8]=x2.x; d[9]=x2.y; d[10]=x2.z; d[11]=x2.w;
    d[12]=x3.x; d[13]=x3.y; d[14]=x3.z; d[15]=x3.w;
}

// One x-step at compile-time buffer parity P. Reads slice x=i0-2+s from
// buf[P]; prefetches slice x+1 into regs early; writes it to buf[P^1] late.
#define STEP(P, V0a, V0b, DP) { \
    const int s = 2*d + (P); \
    const bool doLoad = (s <= 14); \
    float4 a0, a1, a2, a3; \
    if (doLoad) { \
        const float* bp = G + (size_t)(i0 - 1 + s) * OX; \
        a0 = ld4p(bp+gof0); a1 = ld4p(bp+gof1); a2 = ld4p(bp+gof2); \
        if (tl) a3 = ld4p(bp+gof3); \
    } \
    if (act) { \
        const bool doWS = (s >= 2) && (s <= 13); \
        const bool doXY = (s >= 3) && (s <= 14); \
        const bool doXX = (s >= 4); \
        const float* Lr = lds + (P)*SLICEF + oj; \
        float fcn[24]; ld24(fcn, Lr); \
        float v0c[4], dzc0[4], dzc1[4], dzc2[4]; \
        _Pragma("unroll") for (int v=0; v<4; ++v) { \
            v0c[v]  = fcn[6+3*v]; \
            dzc0[v] = fcn[9+3*v]  - fcn[3+3*v]; \
            dzc1[v] = fcn[10+3*v] - fcn[4+3*v]; \
            dzc2[v] = fcn[11+3*v] - fcn[5+3*v]; \
        } \
        if (doWS) { \
            _Pragma("unroll") for (int v=0; v<4; ++v) { \
                float h0 = fcn[12+3*v] - 2.f*fcn[6+3*v] + fcn[3*v];   cls2 = fmaf(h0,h0,cls2); \
                float h1 = fcn[13+3*v] - 2.f*fcn[7+3*v] + fcn[1+3*v]; cls2 = fmaf(h1,h1,cls2); \
                float h2 = fcn[14+3*v] - 2.f*fcn[8+3*v] + fcn[2+3*v]; cls1 = fmaf(h2,h2,cls1); \
            } \
            float p2[16], m2[16]; \
            ld16(p2, Lr + 2*OY + 4); \
            ld16(m2, Lr - 2*OY + 4); \
            _Pragma("unroll") for (int v=0; v<4; ++v) { \
                float h0 = p2[2+3*v] - 2.f*fcn[6+3*v] + m2[2+3*v]; cls2 = fmaf(h0,h0,cls2); \
                float h1 = p2[3+3*v] - 2.f*fcn[7+3*v] + m2[3+3*v]; cls1 = fmaf(h1,h1,cls1); \
            } \
        } \
        float fp[24], fm[24]; \
        ld24(fp, Lr + OY); ld24(fm, Lr - OY); \
        float dyc0[4], dyc1[4]; \
        _Pragma("unroll") for (int v=0; v<4; ++v) { \
            dyc0[v] = fp[3*(v+2)]   - fm[3*(v+2)]; \
            dyc1[v] = fp[3*(v+2)+1] - fm[3*(v+2)+1]; \
        } \
        if (doWS) { \
            _Pragma("unroll") for (int v=0; v<4; ++v) { \
                float ha = (fp[3*(v+3)]   - fm[3*(v+3)])   - (fp[3*(v+1)]   - fm[3*(v+1)]);   cls4 = fmaf(ha,ha,cls4); \
                float hb = (fp[3*(v+3)+1] - fm[3*(v+3)+1]) - (fp[3*(v+1)+1] - fm[3*(v+1)+1]); cls3 = fmaf(hb,hb,cls3); \
                float hc = (fp[3*(v+3)+2] - fm[3*(v+3)+2]) - (fp[3*(v+1)+2] - fm[3*(v+1)+2]); cls1 = fmaf(hc,hc,cls1); \
            } \
        } \
        _Pragma("unroll") for (int v=0; v<4; ++v) { \
            if (doXY) { float h; \
                h = dyc0[v] - DP[0][v]; cls3 = fmaf(h,h,cls3); \
                h = dyc1[v] - DP[1][v]; cls1 = fmaf(h,h,cls1); \
                h = dzc0[v] - DP[2][v]; cls3 = fmaf(h,h,cls3); \
                h = dzc1[v] - DP[3][v]; cls2 = fmaf(h,h,cls2); \
                h = dzc2[v] - DP[4][v]; cls1 = fmaf(h,h,cls1); \
            } \
            DP[0][v] = dyc0[v]; DP[1][v] = dyc1[v]; \
            DP[2][v] = dzc0[v]; DP[3][v] = dzc1[v]; DP[4][v] = dzc2[v]; \
            float w2v = V0a[v], w4v = V0b[v]; \
            if (doXX) { float h = v0c[v] - 2.f*w2v + w4v; cls1 = fmaf(h,h,cls1); } \
            V0b[v] = w2v; V0a[v] = v0c[v]; \
        } \
    } \
    if (doLoad) { \
        float* Lw = lds + ((P)^1)*SLICEF; \
        st4p(Lw+lof0, a0); st4p(Lw+lof1, a1); st4p(Lw+lof2, a2); \
        if (tl) st4p(Lw+lof3, a3); \
    } \
    __syncthreads(); \
}

__global__ __launch_bounds__(256, 4)
void be_partials(const float* __restrict__ g, float* __restrict__ partial) {
    __shared__ float lds[2*SLICEF];
    __shared__ float wsum[4];

    const int tid = threadIdx.x;
    const int bid = blockIdx.x;
    const int is = bid % NSEG;
    int r1 = bid / NSEG;
    const int jt = r1 % 39;
    const int bb = r1 / 39;

    const int j0 = 2 + jt*JT;          // output rows j0..j0+3 (stage j0-2..j0+5)
    const int i0 = 2 + is*IT;          // output slices i0..i0+11
    // slab base: batch + first staged row; each slice's slab is 3840
    // contiguous floats at  + x*OX
    const float* __restrict__ G = g + (size_t)bb*SB + (size_t)(j0-2)*OY;

    // ---- staging offsets: 3 full float4 groups + 192-thread tail group ----
    const bool tl = tid < 192;         // 960 f4 total = 3*256 + 192
    const int gof0 = 4*tid,        lof0 = gof0;
    const int gof1 = 4*(tid+256),  lof1 = gof1;
    const int gof2 = 4*(tid+512),  lof2 = gof2;
    const int gof3 = 4*(tid+768),  lof3 = gof3;

    // ---- compute mapping: thread -> (row cj, z-quad cq); V=4 outputs ----
    const bool act = tid < CTHR;
    int cj = tid / 39, cq = tid - (tid/39)*39;
    if (!act) { cj = 0; cq = 0; }
    const int oj = (cj+2)*OY + 12*cq;   // center-row window base (float index)

    // pipeline state (parity banks: A = even step, B = odd step)
    float v0A0[4], v0A1[4], v0B0[4], v0B1[4];
    float dpA[5][4], dpB[5][4];
    #pragma unroll
    for (int v=0; v<4; ++v) {
        v0A0[v]=v0A1[v]=v0B0[v]=v0B1[v]=0.f;
        #pragma unroll
        for (int q=0; q<5; ++q) { dpA[q][v]=0.f; dpB[q][v]=0.f; }
    }
    float cls1=0.f, cls2=0.f, cls3=0.f, cls4=0.f;

    // warmup: stage slice x = i0-2 into buf 0
    {
        const float* bp = G + (size_t)(i0-2)*OX;
        float4 a0=ld4p(bp+gof0), a1=ld4p(bp+gof1), a2=ld4p(bp+gof2);
        st4p(lds+lof0, a0); st4p(lds+lof1, a1); st4p(lds+lof2, a2);
        if (tl) { float4 a3=ld4p(bp+gof3); st4p(lds+lof3, a3); }
    }
    __syncthreads();

    #pragma unroll 1
    for (int d = 0; d < 8; ++d) {
        STEP(0, v0A0, v0A1, dpA)
        STEP(1, v0B0, v0B1, dpB)
    }

    // fold weight classes (term multiplicities 1,2,3,4; 0.0625 = (0.25)^2)
    float sv = fmaf(2.f, cls2, cls1);
    sv = fmaf(3.f, cls3, sv);
    sv = fmaf(4.f, cls4, sv);
    sv *= 0.0625f;

    #pragma unroll
    for (int off = 32; off > 0; off >>= 1) sv += __shfl_down(sv, off, 64);
    if ((tid & 63) == 0) wsum[tid >> 6] = sv;
    __syncthreads();
    if (tid == 0)
        partial[bid] = (wsum[0] + wsum[1]) + (wsum[2] + wsum[3]);
}

__global__ __launch_bounds__(256)
void be_final(const float* __restrict__ partial, float* __restrict__ out) {
    float s = 0.0f;
    for (int i = threadIdx.x; i < NBLK; i += 256) s += partial[i];
    #pragma unroll
    for (int off = 32; off > 0; off >>= 1) s += __shfl_down(s, off, 64);
    __shared__ float ws[4];
    if ((threadIdx.x & 63) == 0) ws[threadIdx.x >> 6] = s;
    __syncthreads();
    if (threadIdx.x == 0)
        out[0] = ((ws[0] + ws[1]) + (ws[2] + ws[3])) * INV_SIZE;
}

extern "C" void kernel_launch(void* const* d_in, const int* in_sizes, int n_in,
                              void* d_out, int out_size, void* d_ws, size_t ws_size,
                              hipStream_t stream) {
    const float* grid = (const float*)d_in[0];
    float* out = (float*)d_out;
    float* partials = (float*)d_ws;    // 1014 floats

    be_partials<<<dim3(NBLK), dim3(256), 0, stream>>>(grid, partials);
    be_final<<<1, 256, 0, stream>>>(partials, out);
}

// Round 5
// 164.087 us; speedup vs baseline: 1.1159x; 1.1159x over previous
//
#include <hip/hip_runtime.h>

// grid [2,160,160,160,3] fp32; interior outputs (i,j,k) in 2..157 per axis.
//
// Register-pipelined x-march (each staged slice read from LDS exactly once):
//   - within-slice terms (hzz*, hyy*, hyz*) emitted at x = i      (s in [2,13])
//   - hxy*/hxz* at x = i+1 from dy/dz pipelined 2 steps (parity)  (s in [3,14])
//   - hxx0 at x = i+2 from v0 pipelined 4 steps                    (s >= 4)
// LDS slices are FULL-Z AoS rows (480 contiguous floats per y-row):
//   staging is one contiguous 3840-float global slab per slice -> coalesced
//   float4 loads + lane-linear ds_write_b128; compute reads are 16B-aligned
//   ds_read_b128.
// R4: JT=4 (NROW 8), 30.7KB LDS, grid 1014 -> ~4 blocks/CU resident.
// R5: launch_bounds back to (256,3). (256,4) capped VGPR at 64 and spilled
// ~100MB/dispatch to scratch (WRITE_SIZE 22KB->101MB, dur 62->79us). At the
// natural 84 VGPR the HW still fits 4 waves/SIMD, so R4's occupancy stays.
#define OY 480                    // floats per y-row (160 z * 3 comps)
#define OX 76800                  // floats per x-slice
#define SB 12288000               // floats per batch
#define JT 4                      // output rows (y) per block; 39 tiles
#define NROW 8                    // JT + 4 halo rows
#define IT 12                     // output slices (x) per block; 13 segs
#define NSEG 13
#define SLICEF 3840               // floats per slice buffer (8 rows * 480)
#define CTHR 156                  // 4 rows * 39 z-quads (V=4 outputs each)
#define NBLK 1014                 // 2 * 39 * 13
#define INV_SIZE (1.0f/22778496.0f)  // 2*156^3*3

__device__ __forceinline__ float4 ld4p(const float* p){ return *reinterpret_cast<const float4*>(p); }
__device__ __forceinline__ void st4p(float* p, float4 v){ *reinterpret_cast<float4*>(p) = v; }

__device__ __forceinline__ void ld24(float* d, const float* p){
    float4 x0=ld4p(p), x1=ld4p(p+4), x2=ld4p(p+8), x3=ld4p(p+12), x4=ld4p(p+16), x5=ld4p(p+20);
    d[0]=x0.x; d[1]=x0.y; d[2]=x0.z; d[3]=x0.w;
    d[4]=x1.x; d[5]=x1.y; d[6]=x1.z; d[7]=x1.w;
    d[8]=x2.x; d[9]=x2.y; d[10]=x2.z; d[11]=x2.w;
    d[12]=x3.x; d[13]=x3.y; d[14]=x3.z; d[15]=x3.w;
    d[16]=x4.x; d[17]=x4.y; d[18]=x4.z; d[19]=x4.w;
    d[20]=x5.x; d[21]=x5.y; d[22]=x5.z; d[23]=x5.w;
}
__device__ __forceinline__ void ld16(float* d, const float* p){
    float4 x0=ld4p(p), x1=ld4p(p+4), x2=ld4p(p+8), x3=ld4p(p+12);
    d[0]=x0.x; d[1]=x0.y; d[2]=x0.z; d[3]=x0.w;
    d[4]=x1.x; d[5]=x1.y; d[6]=x1.z; d[7]=x1.w;
    d[8]=x2.x; d[9]=x2.y; d[10]=x2.z; d[11]=x2.w;
    d[12]=x3.x; d[13]=x3.y; d[14]=x3.z; d[15]=x3.w;
}

// One x-step at compile-time buffer parity P. Reads slice x=i0-2+s from
// buf[P]; prefetches slice x+1 into regs early; writes it to buf[P^1] late.
#define STEP(P, V0a, V0b, DP) { \
    const int s = 2*d + (P); \
    const bool doLoad = (s <= 14); \
    float4 a0, a1, a2, a3; \
    if (doLoad) { \
        const float* bp = G + (size_t)(i0 - 1 + s) * OX; \
        a0 = ld4p(bp+gof0); a1 = ld4p(bp+gof1); a2 = ld4p(bp+gof2); \
        if (tl) a3 = ld4p(bp+gof3); \
    } \
    if (act) { \
        const bool doWS = (s >= 2) && (s <= 13); \
        const bool doXY = (s >= 3) && (s <= 14); \
        const bool doXX = (s >= 4); \
        const float* Lr = lds + (P)*SLICEF + oj; \
        float fcn[24]; ld24(fcn, Lr); \
        float v0c[4], dzc0[4], dzc1[4], dzc2[4]; \
        _Pragma("unroll") for (int v=0; v<4; ++v) { \
            v0c[v]  = fcn[6+3*v]; \
            dzc0[v] = fcn[9+3*v]  - fcn[3+3*v]; \
            dzc1[v] = fcn[10+3*v] - fcn[4+3*v]; \
            dzc2[v] = fcn[11+3*v] - fcn[5+3*v]; \
        } \
        if (doWS) { \
            _Pragma("unroll") for (int v=0; v<4; ++v) { \
                float h0 = fcn[12+3*v] - 2.f*fcn[6+3*v] + fcn[3*v];   cls2 = fmaf(h0,h0,cls2); \
                float h1 = fcn[13+3*v] - 2.f*fcn[7+3*v] + fcn[1+3*v]; cls2 = fmaf(h1,h1,cls2); \
                float h2 = fcn[14+3*v] - 2.f*fcn[8+3*v] + fcn[2+3*v]; cls1 = fmaf(h2,h2,cls1); \
            } \
            float p2[16], m2[16]; \
            ld16(p2, Lr + 2*OY + 4); \
            ld16(m2, Lr - 2*OY + 4); \
            _Pragma("unroll") for (int v=0; v<4; ++v) { \
                float h0 = p2[2+3*v] - 2.f*fcn[6+3*v] + m2[2+3*v]; cls2 = fmaf(h0,h0,cls2); \
                float h1 = p2[3+3*v] - 2.f*fcn[7+3*v] + m2[3+3*v]; cls1 = fmaf(h1,h1,cls1); \
            } \
        } \
        float fp[24], fm[24]; \
        ld24(fp, Lr + OY); ld24(fm, Lr - OY); \
        float dyc0[4], dyc1[4]; \
        _Pragma("unroll") for (int v=0; v<4; ++v) { \
            dyc0[v] = fp[3*(v+2)]   - fm[3*(v+2)]; \
            dyc1[v] = fp[3*(v+2)+1] - fm[3*(v+2)+1]; \
        } \
        if (doWS) { \
            _Pragma("unroll") for (int v=0; v<4; ++v) { \
                float ha = (fp[3*(v+3)]   - fm[3*(v+3)])   - (fp[3*(v+1)]   - fm[3*(v+1)]);   cls4 = fmaf(ha,ha,cls4); \
                float hb = (fp[3*(v+3)+1] - fm[3*(v+3)+1]) - (fp[3*(v+1)+1] - fm[3*(v+1)+1]); cls3 = fmaf(hb,hb,cls3); \
                float hc = (fp[3*(v+3)+2] - fm[3*(v+3)+2]) - (fp[3*(v+1)+2] - fm[3*(v+1)+2]); cls1 = fmaf(hc,hc,cls1); \
            } \
        } \
        _Pragma("unroll") for (int v=0; v<4; ++v) { \
            if (doXY) { float h; \
                h = dyc0[v] - DP[0][v]; cls3 = fmaf(h,h,cls3); \
                h = dyc1[v] - DP[1][v]; cls1 = fmaf(h,h,cls1); \
                h = dzc0[v] - DP[2][v]; cls3 = fmaf(h,h,cls3); \
                h = dzc1[v] - DP[3][v]; cls2 = fmaf(h,h,cls2); \
                h = dzc2[v] - DP[4][v]; cls1 = fmaf(h,h,cls1); \
            } \
            DP[0][v] = dyc0[v]; DP[1][v] = dyc1[v]; \
            DP[2][v] = dzc0[v]; DP[3][v] = dzc1[v]; DP[4][v] = dzc2[v]; \
            float w2v = V0a[v], w4v = V0b[v]; \
            if (doXX) { float h = v0c[v] - 2.f*w2v + w4v; cls1 = fmaf(h,h,cls1); } \
            V0b[v] = w2v; V0a[v] = v0c[v]; \
        } \
    } \
    if (doLoad) { \
        float* Lw = lds + ((P)^1)*SLICEF; \
        st4p(Lw+lof0, a0); st4p(Lw+lof1, a1); st4p(Lw+lof2, a2); \
        if (tl) st4p(Lw+lof3, a3); \
    } \
    __syncthreads(); \
}

__global__ __launch_bounds__(256, 3)
void be_partials(const float* __restrict__ g, float* __restrict__ partial) {
    __shared__ float lds[2*SLICEF];
    __shared__ float wsum[4];

    const int tid = threadIdx.x;
    const int bid = blockIdx.x;
    const int is = bid % NSEG;
    int r1 = bid / NSEG;
    const int jt = r1 % 39;
    const int bb = r1 / 39;

    const int j0 = 2 + jt*JT;          // output rows j0..j0+3 (stage j0-2..j0+5)
    const int i0 = 2 + is*IT;          // output slices i0..i0+11
    // slab base: batch + first staged row; each slice's slab is 3840
    // contiguous floats at  + x*OX
    const float* __restrict__ G = g + (size_t)bb*SB + (size_t)(j0-2)*OY;

    // ---- staging offsets: 3 full float4 groups + 192-thread tail group ----
    const bool tl = tid < 192;         // 960 f4 total = 3*256 + 192
    const int gof0 = 4*tid,        lof0 = gof0;
    const int gof1 = 4*(tid+256),  lof1 = gof1;
    const int gof2 = 4*(tid+512),  lof2 = gof2;
    const int gof3 = 4*(tid+768),  lof3 = gof3;

    // ---- compute mapping: thread -> (row cj, z-quad cq); V=4 outputs ----
    const bool act = tid < CTHR;
    int cj = tid / 39, cq = tid - (tid/39)*39;
    if (!act) { cj = 0; cq = 0; }
    const int oj = (cj+2)*OY + 12*cq;   // center-row window base (float index)

    // pipeline state (parity banks: A = even step, B = odd step)
    float v0A0[4], v0A1[4], v0B0[4], v0B1[4];
    float dpA[5][4], dpB[5][4];
    #pragma unroll
    for (int v=0; v<4; ++v) {
        v0A0[v]=v0A1[v]=v0B0[v]=v0B1[v]=0.f;
        #pragma unroll
        for (int q=0; q<5; ++q) { dpA[q][v]=0.f; dpB[q][v]=0.f; }
    }
    float cls1=0.f, cls2=0.f, cls3=0.f, cls4=0.f;

    // warmup: stage slice x = i0-2 into buf 0
    {
        const float* bp = G + (size_t)(i0-2)*OX;
        float4 a0=ld4p(bp+gof0), a1=ld4p(bp+gof1), a2=ld4p(bp+gof2);
        st4p(lds+lof0, a0); st4p(lds+lof1, a1); st4p(lds+lof2, a2);
        if (tl) { float4 a3=ld4p(bp+gof3); st4p(lds+lof3, a3); }
    }
    __syncthreads();

    #pragma unroll 1
    for (int d = 0; d < 8; ++d) {
        STEP(0, v0A0, v0A1, dpA)
        STEP(1, v0B0, v0B1, dpB)
    }

    // fold weight classes (term multiplicities 1,2,3,4; 0.0625 = (0.25)^2)
    float sv = fmaf(2.f, cls2, cls1);
    sv = fmaf(3.f, cls3, sv);
    sv = fmaf(4.f, cls4, sv);
    sv *= 0.0625f;

    #pragma unroll
    for (int off = 32; off > 0; off >>= 1) sv += __shfl_down(sv, off, 64);
    if ((tid & 63) == 0) wsum[tid >> 6] = sv;
    __syncthreads();
    if (tid == 0)
        partial[bid] = (wsum[0] + wsum[1]) + (wsum[2] + wsum[3]);
}

__global__ __launch_bounds__(256)
void be_final(const float* __restrict__ partial, float* __restrict__ out) {
    float s = 0.0f;
    for (int i = threadIdx.x; i < NBLK; i += 256) s += partial[i];
    #pragma unroll
    for (int off = 32; off > 0; off >>= 1) s += __shfl_down(s, off, 64);
    __shared__ float ws[4];
    if ((threadIdx.x & 63) == 0) ws[threadIdx.x >> 6] = s;
    __syncthreads();
    if (threadIdx.x == 0)
        out[0] = ((ws[0] + ws[1]) + (ws[2] + ws[3])) * INV_SIZE;
}

extern "C" void kernel_launch(void* const* d_in, const int* in_sizes, int n_in,
                              void* d_out, int out_size, void* d_ws, size_t ws_size,
                              hipStream_t stream) {
    const float* grid = (const float*)d_in[0];
    float* out = (float*)d_out;
    float* partials = (float*)d_ws;    // 1014 floats

    be_partials<<<dim3(NBLK), dim3(256), 0, stream>>>(grid, partials);
    be_final<<<1, 256, 0, stream>>>(partials, out);
}

// Round 6
// 152.398 us; speedup vs baseline: 1.2014x; 1.0767x over previous
//
#include <hip/hip_runtime.h>

// grid [2,160,160,160,3] fp32; interior outputs (i,j,k) in 2..157 per axis.
//
// R6: DPP cross-lane y-stencil. Wave = 16 y-rows x 4 z-quads (DPP row of 16
// lanes = one z-quad, rows 0..15; output rows r in [2,13]). Each lane reads
// ONLY its own row's 24-float z-window from LDS (6 ds_read_b128); y-neighbor
// values (rows +-1,+-2) come from v_mov_dpp row_shr/row_shl on the VALU pipe:
//   dy  = shr1(x) - shl1(x)          (comps 0,1)
//   hyy = shr2(x) - 2x + shl2(x)     (comps 0,1)
//   hyz = shr1(dz) - shl1(dz)        (comps 0,1,2)
// (hyy symmetric, dy/hyz enter squared -> shl/shr orientation cannot change
// the result). x-direction terms keep the verified parity-bank register
// pipeline (hxy/hxz from dy/dz two steps back, hxx from v0 four steps back).
// DS instructions drop ~3.3x vs R5 (24 vs 79 read-instrs per block-step);
// the y-stencil cost moves to the 22%-busy VALU. RST=212 (mod 32 = 20) makes
// the 16-consecutive-row b128 pattern bank-conflict-free.
#define OY 480                    // floats per y-row (160 z * 3 comps)
#define OX 76800                  // floats per x-slice
#define SB 12288000               // floats per batch
#define RST 212                   // padded LDS row stride (floats); 204 used
#define SLICEF (16*RST)           // 3392 floats per slice buffer
#define IT 12                     // output slices (x) per block; 13 segs
#define NSEG 13
#define NBLK 1014                 // 2 * 13(jt) * 3(zt) * 13(is)
#define INV_SIZE (1.0f/22778496.0f)  // 2*156^3*3

#define ROW_SHL1 0x101
#define ROW_SHL2 0x102
#define ROW_SHR1 0x111
#define ROW_SHR2 0x112

template<int CTRL>
__device__ __forceinline__ float dppf(float x){
    return __int_as_float(__builtin_amdgcn_update_dpp(
        0, __float_as_int(x), CTRL, 0xF, 0xF, true));
}

__device__ __forceinline__ float4 ld4p(const float* p){ return *reinterpret_cast<const float4*>(p); }
__device__ __forceinline__ void st4p(float* p, float4 v){ *reinterpret_cast<float4*>(p) = v; }

__device__ __forceinline__ void ld24(float* d, const float* p){
    float4 x0=ld4p(p), x1=ld4p(p+4), x2=ld4p(p+8), x3=ld4p(p+12), x4=ld4p(p+16), x5=ld4p(p+20);
    d[0]=x0.x; d[1]=x0.y; d[2]=x0.z; d[3]=x0.w;
    d[4]=x1.x; d[5]=x1.y; d[6]=x1.z; d[7]=x1.w;
    d[8]=x2.x; d[9]=x2.y; d[10]=x2.z; d[11]=x2.w;
    d[12]=x3.x; d[13]=x3.y; d[14]=x3.z; d[15]=x3.w;
    d[16]=x4.x; d[17]=x4.y; d[18]=x4.z; d[19]=x4.w;
    d[20]=x5.x; d[21]=x5.y; d[22]=x5.z; d[23]=x5.w;
}

// One x-step at compile-time buffer parity P. Reads slice x=i0-2+s from
// buf[P]; prefetches slice x+1 into regs early; writes it to buf[P^1] late.
// DPP ops are gated ONLY by wave-uniform s-windows (never by per-lane vr),
// so halo-row lanes stay active as DPP sources.
#define STEP(P, V0a, V0b, DP) { \
    const int s = 2*d + (P); \
    const bool doLoad = (s <= 14); \
    float4 a0, a1, a2, a3; \
    if (doLoad) { \
        const float* bp = G + (size_t)(i0 - 1 + s) * OX; \
        a0 = ld4p(bp+gof0); a1 = ld4p(bp+gof1); a2 = ld4p(bp+gof2); a3 = ld4p(bp+gof3); \
    } \
    if (qact) { \
        const float* Lr = lds + (P)*SLICEF + oj; \
        float x[24]; ld24(x, Lr); \
        float dz0[4], dz1[4], dz2[4], dy0[4], dy1[4], v0c[4]; \
        _Pragma("unroll") for (int v=0; v<4; ++v) { \
            v0c[v] = x[3*v+6]; \
            dz0[v] = x[3*v+9]  - x[3*v+3]; \
            dz1[v] = x[3*v+10] - x[3*v+4]; \
            dz2[v] = x[3*v+11] - x[3*v+5]; \
            dy0[v] = dppf<ROW_SHR1>(x[3*v+6]) - dppf<ROW_SHL1>(x[3*v+6]); \
            dy1[v] = dppf<ROW_SHR1>(x[3*v+7]) - dppf<ROW_SHL1>(x[3*v+7]); \
        } \
        if (s >= 2 && s <= 13) { \
            _Pragma("unroll") for (int v=0; v<4; ++v) { \
                float c0 = x[3*v+6], c1 = x[3*v+7]; \
                float hy0 = dppf<ROW_SHR2>(c0) - 2.f*c0 + dppf<ROW_SHL2>(c0); \
                float hy1 = dppf<ROW_SHR2>(c1) - 2.f*c1 + dppf<ROW_SHL2>(c1); \
                float yz0 = dppf<ROW_SHR1>(dz0[v]) - dppf<ROW_SHL1>(dz0[v]); \
                float yz1 = dppf<ROW_SHR1>(dz1[v]) - dppf<ROW_SHL1>(dz1[v]); \
                float yz2 = dppf<ROW_SHR1>(dz2[v]) - dppf<ROW_SHL1>(dz2[v]); \
                if (vr) { \
                    float zz0 = x[3*v+12] - 2.f*x[3*v+6] + x[3*v]; \
                    float zz1 = x[3*v+13] - 2.f*x[3*v+7] + x[3*v+1]; \
                    float zz2 = x[3*v+14] - 2.f*x[3*v+8] + x[3*v+2]; \
                    cls2 = fmaf(zz0,zz0,cls2); cls2 = fmaf(zz1,zz1,cls2); cls1 = fmaf(zz2,zz2,cls1); \
                    cls2 = fmaf(hy0,hy0,cls2); cls1 = fmaf(hy1,hy1,cls1); \
                    cls4 = fmaf(yz0,yz0,cls4); cls3 = fmaf(yz1,yz1,cls3); cls1 = fmaf(yz2,yz2,cls1); \
                } \
            } \
        } \
        const bool eXY = vr && (s >= 3) && (s <= 14); \
        const bool eXX = vr && (s >= 4); \
        _Pragma("unroll") for (int v=0; v<4; ++v) { \
            if (eXY) { float h; \
                h = dy0[v] - DP[0][v]; cls3 = fmaf(h,h,cls3); \
                h = dy1[v] - DP[1][v]; cls1 = fmaf(h,h,cls1); \
                h = dz0[v] - DP[2][v]; cls3 = fmaf(h,h,cls3); \
                h = dz1[v] - DP[3][v]; cls2 = fmaf(h,h,cls2); \
                h = dz2[v] - DP[4][v]; cls1 = fmaf(h,h,cls1); \
            } \
            DP[0][v] = dy0[v]; DP[1][v] = dy1[v]; \
            DP[2][v] = dz0[v]; DP[3][v] = dz1[v]; DP[4][v] = dz2[v]; \
            if (eXX) { float h = v0c[v] - 2.f*V0a[v] + V0b[v]; cls1 = fmaf(h,h,cls1); } \
            V0b[v] = V0a[v]; V0a[v] = v0c[v]; \
        } \
    } \
    if (doLoad) { \
        float* Lw = lds + ((P)^1)*SLICEF; \
        if (wv0) st4p(Lw+lof0, a0); \
        if (wv1) st4p(Lw+lof1, a1); \
        if (wv2) st4p(Lw+lof2, a2); \
        if (wv3) st4p(Lw+lof3, a3); \
    } \
    __syncthreads(); \
}

__global__ __launch_bounds__(256)
void be_partials(const float* __restrict__ g, float* __restrict__ partial) {
    __shared__ float lds[2*SLICEF];
    __shared__ float wsum[4];

    const int tid = threadIdx.x;
    const int bid = blockIdx.x;
    const int is = bid % NSEG;
    int r1 = bid / NSEG;
    const int zt = r1 % 3;  r1 /= 3;
    const int jt = r1 % 13;
    const int bb = r1 / 13;

    const int j0  = 2 + jt*12;     // output rows j0..j0+11 (stage j0-2..j0+13)
    const int zlo = 64*zt;         // staged z window zlo..zlo+67 (clamped)
    const int i0  = 2 + is*IT;     // output slices i0..i0+11
    const float* __restrict__ G = g + (size_t)bb*SB + (size_t)(j0-2)*OY + 3*zlo;

    // ---- staging: 848 float4 groups (16 rows x 53; 51 real + 2 pad) ----
    const int vmaxq0 = (480 - 3*zlo) >> 2;
    const int vmaxq = vmaxq0 < 51 ? vmaxq0 : 51;  // valid f4 per row (zt=2: 24)
    int gof0,gof1,gof2,gof3, lof0,lof1,lof2,lof3;
    bool wv0,wv1,wv2,wv3;
    {
        int f, row, pos, vp;
        f = tid;       row = f/53; pos = f - 53*row; vp = pos < vmaxq ? pos : vmaxq-1;
        gof0 = row*OY + 4*vp; lof0 = row*RST + 4*pos; wv0 = pos < vmaxq;
        f = tid + 256; row = f/53; pos = f - 53*row; vp = pos < vmaxq ? pos : vmaxq-1;
        gof1 = row*OY + 4*vp; lof1 = row*RST + 4*pos; wv1 = pos < vmaxq;
        f = tid + 512; row = f/53; pos = f - 53*row; vp = pos < vmaxq ? pos : vmaxq-1;
        gof2 = row*OY + 4*vp; lof2 = row*RST + 4*pos; wv2 = pos < vmaxq;
        if (tid < 80) {
            f = tid + 768; row = f/53; pos = f - 53*row; vp = pos < vmaxq ? pos : vmaxq-1;
            gof3 = row*OY + 4*vp; lof3 = row*RST + 4*pos; wv3 = pos < vmaxq;
        } else { gof3 = 0; lof3 = 0; wv3 = false; }
    }

    // ---- compute mapping: lane = row r (0..15) x z-quad Q (0..15) ----
    const int r = tid & 15;
    const int Q = tid >> 4;
    const int qmax = (zt == 2) ? 7 : 16;       // zt=2 covers out z 130..157
    const bool qact = Q < qmax;                 // wave-granular skip for zt=2
    const bool vr = (r >= 2) && (r <= 13);      // output rows
    const int oj = r*RST + 12*Q;                // own-row window base (floats)

    // x-pipeline state (parity banks: A = even step, B = odd step)
    float v0A0[4], v0A1[4], v0B0[4], v0B1[4];
    float dpA[5][4], dpB[5][4];
    #pragma unroll
    for (int v=0; v<4; ++v) {
        v0A0[v]=v0A1[v]=v0B0[v]=v0B1[v]=0.f;
        #pragma unroll
        for (int q=0; q<5; ++q) { dpA[q][v]=0.f; dpB[q][v]=0.f; }
    }
    float cls1=0.f, cls2=0.f, cls3=0.f, cls4=0.f;

    // warmup: stage slice x = i0-2 into buf 0
    {
        const float* bp = G + (size_t)(i0-2)*OX;
        float4 a0=ld4p(bp+gof0), a1=ld4p(bp+gof1), a2=ld4p(bp+gof2), a3=ld4p(bp+gof3);
        if (wv0) st4p(lds+lof0, a0);
        if (wv1) st4p(lds+lof1, a1);
        if (wv2) st4p(lds+lof2, a2);
        if (wv3) st4p(lds+lof3, a3);
    }
    __syncthreads();

    #pragma unroll 1
    for (int d = 0; d < 8; ++d) {
        STEP(0, v0A0, v0A1, dpA)
        STEP(1, v0B0, v0B1, dpB)
    }

    // fold weight classes (term multiplicities 1,2,3,4; 0.0625 = (0.25)^2)
    float sv = fmaf(2.f, cls2, cls1);
    sv = fmaf(3.f, cls3, sv);
    sv = fmaf(4.f, cls4, sv);
    sv *= 0.0625f;

    #pragma unroll
    for (int off = 32; off > 0; off >>= 1) sv += __shfl_down(sv, off, 64);
    if ((tid & 63) == 0) wsum[tid >> 6] = sv;
    __syncthreads();
    if (tid == 0)
        partial[bid] = (wsum[0] + wsum[1]) + (wsum[2] + wsum[3]);
}

__global__ __launch_bounds__(256)
void be_final(const float* __restrict__ partial, float* __restrict__ out) {
    float s = 0.0f;
    for (int i = threadIdx.x; i < NBLK; i += 256) s += partial[i];
    #pragma unroll
    for (int off = 32; off > 0; off >>= 1) s += __shfl_down(s, off, 64);
    __shared__ float ws[4];
    if ((threadIdx.x & 63) == 0) ws[threadIdx.x >> 6] = s;
    __syncthreads();
    if (threadIdx.x == 0)
        out[0] = ((ws[0] + ws[1]) + (ws[2] + ws[3])) * INV_SIZE;
}

extern "C" void kernel_launch(void* const* d_in, const int* in_sizes, int n_in,
                              void* d_out, int out_size, void* d_ws, size_t ws_size,
                              hipStream_t stream) {
    const float* grid = (const float*)d_in[0];
    float* out = (float*)d_out;
    float* partials = (float*)d_ws;    // 1014 floats

    be_partials<<<dim3(NBLK), dim3(256), 0, stream>>>(grid, partials);
    be_final<<<1, 256, 0, stream>>>(partials, out);
}